// Round 1
// 1297.029 us; speedup vs baseline: 1.1743x; 1.1743x over previous
//
#include <hip/hip_runtime.h>

typedef unsigned short u16;
typedef unsigned int u32;
typedef unsigned long long u64;
typedef __bf16 bf16x8 __attribute__((ext_vector_type(8)));
typedef float f32x4 __attribute__((ext_vector_type(4)));

#define AS1 __attribute__((address_space(1)))
#define AS3 __attribute__((address_space(3)))

__device__ __forceinline__ float bf2f(u32 v) {
    u32 u = v << 16;
    float f;
    __builtin_memcpy(&f, &u, 4);
    return f;
}
__device__ __forceinline__ u16 f2bf(float f) {
    u32 u;
    __builtin_memcpy(&u, &f, 4);
    u32 r = u + 0x7FFFu + ((u >> 16) & 1u);
    return (u16)(r >> 16);
}

// ---------------------------------------------------------------------------
// GEMM: C = A @ Bt^T + bias [RELU]; A [M x K] bf16 row-major, Bt [N x K] bf16.
// m97 structure: BK=32, global_load_lds width 16, 16x16x32 bf16 MFMA,
// XOR-swizzled LDS chunks. grid (N/BN, M/BM).
// ---------------------------------------------------------------------------
template <int BM, int BN, bool RELU>
__global__ __launch_bounds__(256) void gemm_bt(
    const u16* __restrict__ A, const u16* __restrict__ Bt,
    const float* __restrict__ bias, u16* __restrict__ C,
    int lda, int ldb, int ldc, int K)
{
    const int tid = threadIdx.x;
    const int m0 = blockIdx.y * BM;
    const int n0 = blockIdx.x * BN;

    __shared__ bf16x8 As[BM * 4];
    __shared__ bf16x8 Bs[BN * 4];

    constexpr int TM = (BN == 128) ? 4 : 2;
    constexpr int TN = 4;
    const int wave = tid >> 6, lane = tid & 63;
    const int wr = (BN == 128) ? (wave >> 1) : wave;
    const int wc = (BN == 128) ? (wave & 1) : 0;
    const int row_base = wr * (TM * 16);
    const int col_base = wc * 64;
    const int quad = lane >> 4, l16 = lane & 15;

    f32x4 acc[TM][TN] = {};

    for (int k0 = 0; k0 < K; k0 += 32) {
#pragma unroll
        for (int i = 0; i < (BM * 4) / 256; ++i) {
            int s = tid + i * 256;
            int row = s >> 2;
            int gq = (s & 3) ^ ((s >> 3) & 3);
            const u16* gp = A + (size_t)(m0 + row) * lda + k0 + gq * 8;
            __builtin_amdgcn_global_load_lds((AS1 const void*)gp, (AS3 void*)&As[s], 16, 0, 0);
        }
#pragma unroll
        for (int i = 0; i < (BN * 4) / 256; ++i) {
            int s = tid + i * 256;
            int row = s >> 2;
            int gq = (s & 3) ^ ((s >> 3) & 3);
            const u16* gp = Bt + (size_t)(n0 + row) * ldb + k0 + gq * 8;
            __builtin_amdgcn_global_load_lds((AS1 const void*)gp, (AS3 void*)&Bs[s], 16, 0, 0);
        }
        __syncthreads();

        bf16x8 af[TM], bfr[TN];
#pragma unroll
        for (int ri = 0; ri < TM; ++ri) {
            int r = row_base + ri * 16 + l16;
            af[ri] = As[r * 4 + (quad ^ ((r >> 1) & 3))];
        }
#pragma unroll
        for (int cj = 0; cj < TN; ++cj) {
            int c = col_base + cj * 16 + l16;
            bfr[cj] = Bs[c * 4 + (quad ^ ((c >> 1) & 3))];
        }
#pragma unroll
        for (int ri = 0; ri < TM; ++ri)
#pragma unroll
            for (int cj = 0; cj < TN; ++cj)
                acc[ri][cj] = __builtin_amdgcn_mfma_f32_16x16x32_bf16(af[ri], bfr[cj], acc[ri][cj], 0, 0, 0);
        __syncthreads();
    }

#pragma unroll
    for (int ri = 0; ri < TM; ++ri) {
#pragma unroll
        for (int cj = 0; cj < TN; ++cj) {
            const int col = n0 + col_base + cj * 16 + l16;
            const float bv = bias ? bias[col] : 0.0f;
#pragma unroll
            for (int r = 0; r < 4; ++r) {
                const int row = m0 + row_base + ri * 16 + quad * 4 + r;
                float v = acc[ri][cj][r] + bv;
                if (RELU) v = fmaxf(v, 0.0f);
                C[(size_t)row * ldc + col] = f2bf(v);
            }
        }
    }
}

// ---------------------------------------------------------------------------
// Fused attention: per block = 128 q-rows x one (b,h).
//   pass1: S^T = mfma(K,Q) tiles, exact online row max/sum over all 1024 keys
//   pass2: recompute S^T, p = exp(s-m)/l  -> f32x4 store to AW (once),
//          bf16 pack -> per-wave LDS -> PV mfma(V^T, P) -> bf16 ATT
// grid (S/128, B*H), block 256 (4 waves x 32 q-rows each).
// LDS: Qs 16K (reused as Vs in pass2) + Ks 16K + Ps 32K = 64KB -> 2 blocks/CU.
// ---------------------------------------------------------------------------
__global__ __launch_bounds__(256, 2) void attn_fused(
    const u16* __restrict__ Qp, const u16* __restrict__ Kp, const u16* __restrict__ VTp,
    const float* __restrict__ mask, float* __restrict__ AW, u16* __restrict__ ATT,
    int ldq, int ldk)
{
    const int tid = threadIdx.x;
    const int wave = tid >> 6, lane = tid & 63, quad = lane >> 4, l16 = lane & 15;
    const int z = blockIdx.y, b = z >> 4, h = z & 15;
    const int m0 = blockIdx.x << 7;

    const u16* Q = Qp + (size_t)(b * 1024 + m0) * ldq + h * 64;
    const u16* K = Kp + (size_t)(b * 1024) * ldk + h * 64;
    const u16* VT = VTp + ((size_t)z << 16);
    const float* Mq = mask + ((size_t)b << 20) + ((size_t)m0 << 10);
    float* AWp = AW + ((size_t)z << 20) + ((size_t)m0 << 10);
    u16* Op = ATT + ((size_t)(b * 1024 + m0) << 10) + h * 64;

    __shared__ bf16x8 Qs[128 * 8];     // Q tile [128 q][64 d]; reused as V^T tile pass2
    __shared__ bf16x8 Ks[128 * 8];     // K tile [128 k][64 d]
    __shared__ u64 Ps[4][1024];        // per-wave P [32 q][128 k] bf16

    bf16x8* Vs = Qs;                   // [64 d][128 k], pass2 only (Qs dead by then)

    // ---- stage Q once ----
#pragma unroll
    for (int i = 0; i < 4; ++i) {
        int s = tid + i * 256;
        int row = s >> 3, ch = s & 7;
        const u16* gp = Q + (size_t)row * ldq + ((ch ^ (row & 7)) << 3);
        __builtin_amdgcn_global_load_lds((AS1 const void*)gp, (AS3 void*)&Qs[s], 16, 0, 0);
    }
    __syncthreads();

    // ---- hoist Q fragments (B-operand: row=q via l16, chunk=dstep*4+quad) ----
    bf16x8 bq[2][2];
#pragma unroll
    for (int qj = 0; qj < 2; ++qj) {
        int q = wave * 32 + qj * 16 + l16;
#pragma unroll
        for (int dstep = 0; dstep < 2; ++dstep)
            bq[qj][dstep] = Qs[q * 8 + ((dstep * 4 + quad) ^ (q & 7))];
    }

    float m_run[2] = {-1e30f, -1e30f};
    float l_run[2] = {0.0f, 0.0f};

    // ================= pass 1: exact row max + sum =================
    for (int kt = 0; kt < 8; ++kt) {
#pragma unroll
        for (int i = 0; i < 4; ++i) {
            int s = tid + i * 256;
            int row = s >> 3, ch = s & 7;
            const u16* gp = K + (size_t)(kt * 128 + row) * ldk + ((ch ^ (row & 7)) << 3);
            __builtin_amdgcn_global_load_lds((AS1 const void*)gp, (AS3 void*)&Ks[s], 16, 0, 0);
        }
        __syncthreads();

        f32x4 acc[8][2] = {};
#pragma unroll
        for (int ki = 0; ki < 8; ++ki) {
            int key = ki * 16 + l16;
            bf16x8 ka0 = Ks[key * 8 + (quad ^ (key & 7))];
            bf16x8 ka1 = Ks[key * 8 + ((4 + quad) ^ (key & 7))];
#pragma unroll
            for (int qj = 0; qj < 2; ++qj) {
                acc[ki][qj] = __builtin_amdgcn_mfma_f32_16x16x32_bf16(ka0, bq[qj][0], acc[ki][qj], 0, 0, 0);
                acc[ki][qj] = __builtin_amdgcn_mfma_f32_16x16x32_bf16(ka1, bq[qj][1], acc[ki][qj], 0, 0, 0);
            }
        }
#pragma unroll
        for (int qj = 0; qj < 2; ++qj) {
            const float* mrow = Mq + (((size_t)(wave * 32 + qj * 16 + l16)) << 10) + kt * 128 + quad * 4;
            float mx = -1e30f;
#pragma unroll
            for (int ki = 0; ki < 8; ++ki) {
                f32x4 mk = *(const f32x4*)(mrow + ki * 16);
#pragma unroll
                for (int r = 0; r < 4; ++r) {
                    float s = fmaf(acc[ki][qj][r], 0.125f, mk[r]);
                    acc[ki][qj][r] = s;
                    mx = fmaxf(mx, s);
                }
            }
            mx = fmaxf(mx, __shfl_xor(mx, 16));
            mx = fmaxf(mx, __shfl_xor(mx, 32));
            float mnew = fmaxf(m_run[qj], mx);
            float sum = 0.0f;
#pragma unroll
            for (int ki = 0; ki < 8; ++ki)
#pragma unroll
                for (int r = 0; r < 4; ++r)
                    sum += __expf(acc[ki][qj][r] - mnew);
            sum += __shfl_xor(sum, 16);
            sum += __shfl_xor(sum, 32);
            l_run[qj] = l_run[qj] * __expf(m_run[qj] - mnew) + sum;
            m_run[qj] = mnew;
        }
        __syncthreads();
    }

    // ================= pass 2: P store + PV =================
    const float invl[2] = {1.0f / l_run[0], 1.0f / l_run[1]};
    u64* Pw = Ps[wave];
    const bf16x8* Pr = (const bf16x8*)Ps[wave];
    f32x4 opv[4][2] = {};   // [d-subtile][qj]

    for (int kt = 0; kt < 8; ++kt) {
#pragma unroll
        for (int i = 0; i < 4; ++i) {
            int s = tid + i * 256;
            int row = s >> 3, ch = s & 7;
            const u16* gp = K + (size_t)(kt * 128 + row) * ldk + ((ch ^ (row & 7)) << 3);
            __builtin_amdgcn_global_load_lds((AS1 const void*)gp, (AS3 void*)&Ks[s], 16, 0, 0);
        }
#pragma unroll
        for (int i = 0; i < 4; ++i) {
            int s = tid + i * 256;
            int row = s >> 4, ch = s & 15;   // d-row, key-chunk
            const u16* gp = VT + ((size_t)row << 10) + kt * 128 + ((ch ^ (row & 15)) << 3);
            __builtin_amdgcn_global_load_lds((AS1 const void*)gp, (AS3 void*)&Vs[s], 16, 0, 0);
        }
        __syncthreads();

        // recompute S^T, normalize, emit AW + P_lds
#pragma unroll
        for (int ki = 0; ki < 8; ++ki) {
            int key = ki * 16 + l16;
            bf16x8 ka0 = Ks[key * 8 + (quad ^ (key & 7))];
            bf16x8 ka1 = Ks[key * 8 + ((4 + quad) ^ (key & 7))];
#pragma unroll
            for (int qj = 0; qj < 2; ++qj) {
                f32x4 a = {};
                a = __builtin_amdgcn_mfma_f32_16x16x32_bf16(ka0, bq[qj][0], a, 0, 0, 0);
                a = __builtin_amdgcn_mfma_f32_16x16x32_bf16(ka1, bq[qj][1], a, 0, 0, 0);
                const size_t roff = ((size_t)(wave * 32 + qj * 16 + l16)) << 10;
                f32x4 mk = *(const f32x4*)(Mq + roff + kt * 128 + ki * 16 + quad * 4);
                f32x4 p;
#pragma unroll
                for (int r = 0; r < 4; ++r)
                    p[r] = __expf(fmaf(a[r], 0.125f, mk[r]) - m_run[qj]) * invl[qj];
                *(f32x4*)(AWp + roff + kt * 128 + ki * 16 + quad * 4) = p;
                u64 pk = (u64)f2bf(p[0]) | ((u64)f2bf(p[1]) << 16)
                       | ((u64)f2bf(p[2]) << 32) | ((u64)f2bf(p[3]) << 48);
                int q = qj * 16 + l16;
                Pw[q * 32 + ((ki * 4 + quad) ^ ((q & 7) << 1))] = pk;
            }
        }

        // PV: mfma(V^T-frag, P-frag) -> C[d][q]
#pragma unroll
        for (int ks = 0; ks < 4; ++ks) {
            bf16x8 pb[2];
#pragma unroll
            for (int qj = 0; qj < 2; ++qj) {
                int q = qj * 16 + l16;
                pb[qj] = Pr[q * 16 + ((ks * 4 + quad) ^ (q & 7))];
            }
#pragma unroll
            for (int ds = 0; ds < 4; ++ds) {
                int d = ds * 16 + l16;
                bf16x8 va = Vs[d * 16 + ((ks * 4 + quad) ^ (d & 15))];
                opv[ds][0] = __builtin_amdgcn_mfma_f32_16x16x32_bf16(va, pb[0], opv[ds][0], 0, 0, 0);
                opv[ds][1] = __builtin_amdgcn_mfma_f32_16x16x32_bf16(va, pb[1], opv[ds][1], 0, 0, 0);
            }
        }
        __syncthreads();
    }

    // epilogue: C[d][q] -> ATT[q][d], 4 consecutive d per lane -> u64 store
#pragma unroll
    for (int ds = 0; ds < 4; ++ds)
#pragma unroll
        for (int qj = 0; qj < 2; ++qj) {
            int q = wave * 32 + qj * 16 + l16;
            f32x4 v = opv[ds][qj];
            u64 o = (u64)f2bf(v[0]) | ((u64)f2bf(v[1]) << 16)
                  | ((u64)f2bf(v[2]) << 32) | ((u64)f2bf(v[3]) << 48);
            *(u64*)(Op + (((size_t)q) << 10) + ds * 16 + quad * 4) = o;
        }
}

// ---------------------------------------------------------------------------
// fp32 -> bf16 transpose: dst[c][r] = cvt(src[r][c]); grid (C/32, R/32), block (32,8)
// ---------------------------------------------------------------------------
__global__ void transpose_cvt(const float* __restrict__ src, u16* __restrict__ dst, int R, int C)
{
    __shared__ u16 t[32][33];
    const int c0 = blockIdx.x << 5, r0 = blockIdx.y << 5;
    const int tx = threadIdx.x, ty = threadIdx.y;
#pragma unroll
    for (int i = 0; i < 4; ++i) {
        int r = r0 + ty * 4 + i;
        t[ty * 4 + i][tx] = f2bf(src[(size_t)r * C + c0 + tx]);
    }
    __syncthreads();
#pragma unroll
    for (int i = 0; i < 4; ++i) {
        int c = c0 + ty * 4 + i;
        dst[(size_t)c * R + r0 + tx] = t[tx][ty * 4 + i];
    }
}

// fp32 -> bf16 straight copy, 4 elems/thread; grid = n/1024
__global__ __launch_bounds__(256) void cvt4(const float* __restrict__ src, u16* __restrict__ dst)
{
    size_t i = (size_t)blockIdx.x * 256 + threadIdx.x;
    f32x4 v = ((const f32x4*)src)[i];
    u64 o = (u64)f2bf(v[0]) | ((u64)f2bf(v[1]) << 16) | ((u64)f2bf(v[2]) << 32) | ((u64)f2bf(v[3]) << 48);
    ((u64*)dst)[i] = o;
}

// V columns (stride ld) -> VT [(b*16+h)][64][1024] ; grid (32, 2, 64), block (32,8)
__global__ void transpose_v(const u16* __restrict__ v, u16* __restrict__ vt, int ld)
{
    __shared__ u16 t[32][33];
    const int z = blockIdx.z, b = z >> 4, h = z & 15;
    const int s0 = blockIdx.x << 5, d0 = blockIdx.y << 5;
    const int tx = threadIdx.x, ty = threadIdx.y;
    const u16* src = v + (size_t)(b << 10) * ld + h * 64;
#pragma unroll
    for (int i = 0; i < 4; ++i) {
        int s = s0 + ty * 4 + i;
        t[ty * 4 + i][tx] = src[(size_t)s * ld + d0 + tx];
    }
    __syncthreads();
    u16* dst = vt + ((size_t)z << 16);
#pragma unroll
    for (int i = 0; i < 4; ++i) {
        int d = d0 + ty * 4 + i;
        dst[((size_t)d << 10) + s0 + tx] = t[tx][ty * 4 + i];
    }
}

// concat up to 3 length-n fp32 vectors; launch grid = (#segs*n)/256
__global__ void concat3(const float* __restrict__ a, const float* __restrict__ b,
                        const float* __restrict__ c, float* __restrict__ o, int n)
{
    int i = blockIdx.x * 256 + threadIdx.x;
    float v = (i < n) ? a[i] : (i < 2 * n) ? b[i - n] : c[i - 2 * n];
    o[i] = v;
}

// ---------------------------------------------------------------------------
// out = LayerNorm(a + b) * g + be ; a bf16, b fp32 (B_F32) or bf16
// ---------------------------------------------------------------------------
template <bool B_F32>
__global__ __launch_bounds__(256) void add_ln(
    const u16* __restrict__ a, const void* __restrict__ bvp,
    const float* __restrict__ g, const float* __restrict__ be,
    u16* __restrict__ out, float* __restrict__ outf)
{
    const size_t row = blockIdx.x;
    const int t = threadIdx.x;
    uint2 va = ((const uint2*)(a + (row << 10)))[t];
    float f0 = bf2f(va.x & 0xffffu), f1 = bf2f(va.x >> 16);
    float f2 = bf2f(va.y & 0xffffu), f3 = bf2f(va.y >> 16);
    if (B_F32) {
        f32x4 vb = ((const f32x4*)((const float*)bvp + (row << 10)))[t];
        f0 += vb[0]; f1 += vb[1]; f2 += vb[2]; f3 += vb[3];
    } else {
        uint2 vb = ((const uint2*)((const u16*)bvp + (row << 10)))[t];
        f0 += bf2f(vb.x & 0xffffu); f1 += bf2f(vb.x >> 16);
        f2 += bf2f(vb.y & 0xffffu); f3 += bf2f(vb.y >> 16);
    }
    float s = f0 + f1 + f2 + f3;
    float q = f0 * f0 + f1 * f1 + f2 * f2 + f3 * f3;
#pragma unroll
    for (int off = 32; off > 0; off >>= 1) {
        s += __shfl_xor(s, off);
        q += __shfl_xor(q, off);
    }
    __shared__ float rs[4], rq[4];
    const int wave = t >> 6, lane = t & 63;
    if (lane == 0) { rs[wave] = s; rq[wave] = q; }
    __syncthreads();
    s = rs[0] + rs[1] + rs[2] + rs[3];
    q = rq[0] + rq[1] + rq[2] + rq[3];
    const float mean = s * (1.0f / 1024.0f);
    const float var = q * (1.0f / 1024.0f) - mean * mean;
    const float rstd = rsqrtf(var + 1e-5f);
    f32x4 vg = ((const f32x4*)g)[t];
    f32x4 ve = ((const f32x4*)be)[t];
    float r0 = (f0 - mean) * rstd * vg[0] + ve[0];
    float r1 = (f1 - mean) * rstd * vg[1] + ve[1];
    float r2 = (f2 - mean) * rstd * vg[2] + ve[2];
    float r3 = (f3 - mean) * rstd * vg[3] + ve[3];
    if (out) {
        u32 o0 = (u32)f2bf(r0) | ((u32)f2bf(r1) << 16);
        u32 o1 = (u32)f2bf(r2) | ((u32)f2bf(r3) << 16);
        ((uint2*)(out + (row << 10)))[t] = make_uint2(o0, o1);
    }
    if (outf) {
        f32x4 o; o[0] = r0; o[1] = r1; o[2] = r2; o[3] = r3;
        ((f32x4*)(outf + (row << 10)))[t] = o;
    }
}

// ---------------------------------------------------------------------------
extern "C" void kernel_launch(void* const* d_in, const int* in_sizes, int n_in,
                              void* d_out, int out_size, void* d_ws, size_t ws_size,
                              hipStream_t stream)
{
    const float* X    = (const float*)d_in[0];
    const float* ENC  = (const float*)d_in[1];
    const float* MPAD = (const float*)d_in[2];   // cross-attn mask (B,1,S,S)
    const float* MSUB = (const float*)d_in[3];   // self-attn mask
    const float* Wq1 = (const float*)d_in[4],  *bq1 = (const float*)d_in[5];
    const float* Wk1 = (const float*)d_in[6],  *bk1 = (const float*)d_in[7];
    const float* Wv1 = (const float*)d_in[8],  *bv1 = (const float*)d_in[9];
    const float* Wo1 = (const float*)d_in[10], *bo1 = (const float*)d_in[11];
    const float* Wq2 = (const float*)d_in[12], *bq2 = (const float*)d_in[13];
    const float* Wk2 = (const float*)d_in[14], *bk2 = (const float*)d_in[15];
    const float* Wv2 = (const float*)d_in[16], *bv2 = (const float*)d_in[17];
    const float* Wo2 = (const float*)d_in[18], *bo2 = (const float*)d_in[19];
    const float* Wf1 = (const float*)d_in[20], *bf1 = (const float*)d_in[21];
    const float* Wf2 = (const float*)d_in[22], *bf2v = (const float*)d_in[23];
    const float* g1 = (const float*)d_in[24], *be1 = (const float*)d_in[25];
    const float* g2 = (const float*)d_in[26], *be2 = (const float*)d_in[27];
    const float* g3 = (const float*)d_in[28], *be3 = (const float*)d_in[29];

    float* OUT3 = (float*)d_out;
    float* AW1  = OUT3 + 4194304;      // (B,H,S,S) fp32
    float* AW2  = AW1 + 67108864;

    u16* ws = (u16*)d_ws;
    const size_t M1 = 1048576;
    // weights: WTq1|WTk1|WTv1 contiguous -> fused QKV1 [3072][1024]
    u16* WTqkv1 = ws + 0 * M1;                    // 0..2
    u16* WTo1 = ws + 3 * M1;
    u16* WTkv2 = ws + 4 * M1;                     // WTk2|WTv2 [2048][1024]
    u16* WTq2 = ws + 6 * M1;
    u16* WTo2 = ws + 7 * M1;
    u16* WTF1 = ws + 8 * M1;                      // [4096][1024]
    u16* WTF2 = ws + 12 * M1;                     // [1024][4096]
    u16* Xbf  = ws + 16 * M1;
    u16* ENCb = ws + 20 * M1;
    u16* QKV1 = ws + 24 * M1;                     // [4096][3072]; reused: Q2b/KV2, then Hb
    u16* Q2b  = ws + 24 * M1;                     // [4096][1024]
    u16* KV2  = ws + 28 * M1;                     // [4096][2048]
    u16* Hb   = ws + 24 * M1;                     // FFN hidden [4096][4096]
    u16* VT   = ws + 36 * M1;                     // [64][64][1024]
    u16* ATT  = ws + 40 * M1;
    u16* TMP  = ws + 44 * M1;
    u16* O1   = ws + 48 * M1;
    u16* O2   = ws + 52 * M1;
    float* BQKV1 = (float*)(ws + 56 * M1);        // 3072 fp32
    float* BKV2  = BQKV1 + 3072;                  // 2048 fp32

    const dim3 tb(32, 8);
    // --- input/weight conversion ---
    cvt4<<<4096, 256, 0, stream>>>(X, Xbf);
    cvt4<<<4096, 256, 0, stream>>>(ENC, ENCb);
    transpose_cvt<<<dim3(32, 32), tb, 0, stream>>>(Wq1, WTqkv1, 1024, 1024);
    transpose_cvt<<<dim3(32, 32), tb, 0, stream>>>(Wk1, WTqkv1 + 1 * M1, 1024, 1024);
    transpose_cvt<<<dim3(32, 32), tb, 0, stream>>>(Wv1, WTqkv1 + 2 * M1, 1024, 1024);
    transpose_cvt<<<dim3(32, 32), tb, 0, stream>>>(Wo1, WTo1, 1024, 1024);
    transpose_cvt<<<dim3(32, 32), tb, 0, stream>>>(Wk2, WTkv2, 1024, 1024);
    transpose_cvt<<<dim3(32, 32), tb, 0, stream>>>(Wv2, WTkv2 + 1 * M1, 1024, 1024);
    transpose_cvt<<<dim3(32, 32), tb, 0, stream>>>(Wq2, WTq2, 1024, 1024);
    transpose_cvt<<<dim3(32, 32), tb, 0, stream>>>(Wo2, WTo2, 1024, 1024);
    transpose_cvt<<<dim3(128, 32), tb, 0, stream>>>(Wf1, WTF1, 1024, 4096);
    transpose_cvt<<<dim3(32, 128), tb, 0, stream>>>(Wf2, WTF2, 4096, 1024);
    concat3<<<12, 256, 0, stream>>>(bq1, bk1, bv1, BQKV1, 1024);
    concat3<<<8, 256, 0, stream>>>(bk2, bv2, bv2, BKV2, 1024);

    // ---------------- self-attention ----------------
    gemm_bt<128, 128, false><<<dim3(24, 32), 256, 0, stream>>>(
        Xbf, WTqkv1, BQKV1, QKV1, 1024, 1024, 3072, 1024);
    transpose_v<<<dim3(32, 2, 64), tb, 0, stream>>>(QKV1 + 2048, VT, 3072);
    attn_fused<<<dim3(8, 64), 256, 0, stream>>>(
        QKV1, QKV1 + 1024, VT, MSUB, AW1, ATT, 3072, 3072);
    gemm_bt<128, 64, false><<<dim3(16, 32), 256, 0, stream>>>(
        ATT, WTo1, bo1, TMP, 1024, 1024, 1024, 1024);
    add_ln<true><<<4096, 256, 0, stream>>>(TMP, X, g1, be1, O1, nullptr);

    // ---------------- cross-attention ----------------
    gemm_bt<128, 64, false><<<dim3(16, 32), 256, 0, stream>>>(
        O1, WTq2, bq2, Q2b, 1024, 1024, 1024, 1024);
    gemm_bt<128, 128, false><<<dim3(16, 32), 256, 0, stream>>>(
        ENCb, WTkv2, BKV2, KV2, 1024, 1024, 2048, 1024);
    transpose_v<<<dim3(32, 2, 64), tb, 0, stream>>>(KV2 + 1024, VT, 2048);
    attn_fused<<<dim3(8, 64), 256, 0, stream>>>(
        Q2b, KV2, VT, MPAD, AW2, ATT, 1024, 2048);
    gemm_bt<128, 64, false><<<dim3(16, 32), 256, 0, stream>>>(
        ATT, WTo2, bo2, TMP, 1024, 1024, 1024, 1024);
    add_ln<false><<<4096, 256, 0, stream>>>(TMP, O1, g2, be2, O2, nullptr);

    // ---------------- FFN ----------------
    gemm_bt<128, 128, true><<<dim3(32, 32), 256, 0, stream>>>(
        O2, WTF1, bf1, Hb, 1024, 1024, 4096, 1024);
    gemm_bt<128, 128, false><<<dim3(8, 32), 256, 0, stream>>>(
        Hb, WTF2, bf2v, TMP, 4096, 4096, 1024, 4096);
    add_ln<false><<<4096, 256, 0, stream>>>(TMP, O2, g3, be3, nullptr, OUT3);
}